// Round 8
// baseline (170.718 us; speedup 1.0000x reference)
//
#include <hip/hip_runtime.h>
#include <cstdint>
#include <cstddef>

typedef __bf16 bf16;
typedef bf16 bf16x8 __attribute__((ext_vector_type(8)));
typedef float f32x4 __attribute__((ext_vector_type(4)));

// ---------------- attention (tiny, exact f32) ----------------
__global__ __launch_bounds__(256) void attn_kernel(
    const float* __restrict__ ref, const float* __restrict__ w1,
    const float* __restrict__ w2, const float* __restrict__ b2,
    const float* __restrict__ bias, float* __restrict__ attn,
    float* __restrict__ aggb) {
  const int b = blockIdx.x, t = threadIdx.x;
  __shared__ float pooled[256];
  __shared__ float hsh[65];
  __shared__ float ash[4];
  {
    const float* r = ref + ((size_t)b * 256 + t) * 64;
    float s = 0.f;
    #pragma unroll
    for (int l = 0; l < 64; l += 4) {
      float4 v = *(const float4*)(r + l);
      s += v.x + v.y + v.z + v.w;
    }
    pooled[t] = s * (1.0f / 64.0f);
  }
  __syncthreads();
  if (t < 65) {
    const float* w = w1 + t * 256;
    float s = 0.f;
    for (int p = 0; p < 256; ++p) s += pooled[p] * w[p];
    hsh[t] = fmaxf(s, 0.f);
  }
  __syncthreads();
  if (t == 0) {
    float lg[4];
    for (int k = 0; k < 4; ++k) {
      float s = b2[k];
      for (int j = 0; j < 65; ++j) s += hsh[j] * w2[k * 65 + j];
      lg[k] = s * (1.0f / 34.0f);
    }
    float m = fmaxf(fmaxf(lg[0], lg[1]), fmaxf(lg[2], lg[3]));
    float e[4], se = 0.f;
    for (int k = 0; k < 4; ++k) { e[k] = expf(lg[k] - m); se += e[k]; }
    float inv = 1.0f / se;
    for (int k = 0; k < 4; ++k) { float a = e[k] * inv; ash[k] = a; attn[b * 4 + k] = a; }
  }
  __syncthreads();
  {
    float s = 0.f;
    for (int k = 0; k < 4; ++k) s += ash[k] * bias[k * 256 + t];
    aggb[b * 256 + t] = s;
  }
}

// ---------------- weight aggregation -> bf16, [b][o][s*256+i] ----------------
__global__ __launch_bounds__(256) void aggw_kernel(
    const float* __restrict__ weight, const float* __restrict__ attn,
    bf16* __restrict__ Wagg) {
  const int o = blockIdx.x, b = blockIdx.y, i = threadIdx.x;
  const float a0 = attn[b * 4 + 0], a1 = attn[b * 4 + 1];
  const float a2 = attn[b * 4 + 2], a3 = attn[b * 4 + 3];
  const size_t ks = (size_t)256 * 256 * 3;
  const float* w = weight + ((size_t)o * 256 + i) * 3;
  bf16* dst = Wagg + ((size_t)(b * 256 + o)) * 768 + i;
  #pragma unroll
  for (int s = 0; s < 3; ++s) {
    float v = a0 * w[s] + a1 * w[ks + s] + a2 * w[2 * ks + s] + a3 * w[3 * ks + s];
    dst[s * 256] = (bf16)v;
  }
}

// ---------------- main conv-as-GEMM, 128x128 tile, K=768 ----------------
// X-only LDS (single-buffered, R5's proven staging+swizzle); W fragments
// loaded DIRECTLY global->VGPR (L2-hot per XCD via the block swizzle) with
// compile-time offsets. No W staging => no per-step barriers, no vmcnt
// drains: each i-block is one barrier-free region of 96 MFMAs the compiler
// can pipeline. Default launch bounds — NEVER cap the allocator (R3/R6/R7).
__global__ __launch_bounds__(256) void conv_kernel(
    const float* __restrict__ x, const bf16* __restrict__ Wagg,
    const float* __restrict__ aggb, float* __restrict__ out) {
  __shared__ bf16 Xl[130 * 64];      // 16.25 KB (single, swaps per i-block)
  const int tid = threadIdx.x;
  const int lane = tid & 63, wid = tid >> 6;
  // XCD swizzle: 2048 blocks, 8 XCDs -> consecutive swz ids per XCD = 1 batch.
  const int bid = blockIdx.x;
  const int swz = (bid & 7) * 256 + (bid >> 3);
  const int b  = swz >> 6;
  const int ot = (swz >> 5) & 1;
  const int lt = swz & 31;
  const int l0 = lt * 128, o0 = ot * 128;
  const int wm = wid >> 1, wn = wid & 1;
  const float* xb = x + (size_t)b * 256 * 4096;
  // per-lane W fragment base: row = o0 + wm*64 + (lane&15), k-sub = (lane>>4)*8
  const bf16* wlane = Wagg + ((size_t)(b * 256 + o0 + wm * 64 + (lane & 15))) * 768
                      + ((lane >> 4) << 3);
  f32x4 acc[4][4] = {};

  // ---- fused X staging (f32 -> bf16 transpose into swizzled LDS) ----
  const int sg = tid >> 5, lc = tid & 31;
  const float* xmain = xb + ((size_t)sg * 8) * 4096 + l0 + lc * 4;
  const int eg = (tid >> 1) & 7;
  const int erow = (tid & 1) ? 129 : 0;
  const int el = (tid & 1) ? (l0 + 128) : (l0 - 1);
  const bool edge_ok = (el >= 0) && (el < 4096);

  float4 xv[8];

  auto load_x = [&](int ib) {
    const float* p = xmain + (size_t)ib * 64 * 4096;
    #pragma unroll
    for (int r = 0; r < 8; ++r)
      xv[r] = *(const float4*)(p + (size_t)r * 4096);
  };
  // writes ib's tile; edge columns loaded inline (16 lanes, L2-hot)
  auto write_x = [&](int ib) {
    char* base = (char*)&Xl[0];
    #pragma unroll
    for (int q = 0; q < 4; ++q) {
      const int row = lc * 4 + 1 + q;
      bf16x8 pk;
      #pragma unroll
      for (int r = 0; r < 8; ++r) pk[r] = (bf16)(((const float*)&xv[r])[q]);
      *(bf16x8*)(base + row * 128 + ((sg ^ (row & 7)) << 4)) = pk;
    }
    if (tid < 16) {
      bf16x8 pe;
      #pragma unroll
      for (int r = 0; r < 8; ++r) {
        float v = edge_ok ? xb[(size_t)(ib * 64 + eg * 8 + r) * 4096 + el] : 0.f;
        pe[r] = (bf16)v;
      }
      *(bf16x8*)(base + erow * 128 + ((eg ^ (erow & 7)) << 4)) = pe;
    }
  };

  // prologue
  load_x(0);
  write_x(0);
  __syncthreads();   // X ds_writes visible

  for (int ib = 0; ib < 4; ++ib) {
    if (ib < 3) load_x(ib + 1);          // early-issue next X tile (T14)
    const char* xbuf = (const char*)&Xl[0];
    #pragma unroll
    for (int s = 0; s < 3; ++s) {
      const int kbase = s * 256 + ib * 64;
      #pragma unroll
      for (int kk = 0; kk < 2; ++kk) {
        bf16x8 af[4], bfr[4];
        #pragma unroll
        for (int m = 0; m < 4; ++m)
          af[m] = *(const bf16x8*)(wlane + (size_t)m * 16 * 768 + kbase + kk * 32);
        const int sub = (lane >> 4) + kk * 4;
        #pragma unroll
        for (int n = 0; n < 4; ++n) {
          int row = wn * 64 + n * 16 + (lane & 15) + s;   // +s = conv shift
          bfr[n] = *(const bf16x8*)(xbuf + row * 128 + ((sub ^ (row & 7)) << 4));
        }
        #pragma unroll
        for (int m = 0; m < 4; ++m)
          #pragma unroll
          for (int n = 0; n < 4; ++n)
            acc[m][n] = __builtin_amdgcn_mfma_f32_16x16x32_bf16(af[m], bfr[n], acc[m][n], 0, 0, 0);
      }
    }
    // all waves must finish reading Xl before the next tile overwrites it
    if (ib < 3) {
      __syncthreads();
      write_x(ib + 1);  // bf16-convert + transposed ds_write of next X tile
      __syncthreads();  // writes visible before next i-block's reads
    }
  }

  const int b256 = b * 256;
  #pragma unroll
  for (int m = 0; m < 4; ++m) {
    const int ob = o0 + wm * 64 + m * 16 + ((lane >> 4) << 2);
    float bb[4];
    #pragma unroll
    for (int r = 0; r < 4; ++r) bb[r] = aggb[b256 + ob + r];
    #pragma unroll
    for (int n = 0; n < 4; ++n) {
      const int l = l0 + wn * 64 + n * 16 + (lane & 15);
      f32x4 v = acc[m][n];
      #pragma unroll
      for (int r = 0; r < 4; ++r)
        out[((size_t)(b256 + ob + r)) * 4096 + l] = v[r] + bb[r];
    }
  }
}

extern "C" void kernel_launch(void* const* d_in, const int* in_sizes, int n_in,
                              void* d_out, int out_size, void* d_ws, size_t ws_size,
                              hipStream_t stream) {
  const float* ref    = (const float*)d_in[0];
  const float* x      = (const float*)d_in[1];
  const float* w1     = (const float*)d_in[2];
  const float* w2     = (const float*)d_in[3];
  const float* b2     = (const float*)d_in[4];
  const float* weight = (const float*)d_in[5];
  const float* bias   = (const float*)d_in[6];
  float* out = (float*)d_out;
  char* ws = (char*)d_ws;

  const size_t WAGG_BYTES = (size_t)32 * 256 * 768 * 2;    // 12,582,912
  bf16* Wagg  = (bf16*)ws;
  float* attn = (float*)(ws + WAGG_BYTES);
  float* aggb = (float*)(ws + WAGG_BYTES + 512);

  attn_kernel<<<32, 256, 0, stream>>>(ref, w1, w2, b2, bias, attn, aggb);
  aggw_kernel<<<dim3(256, 32), 256, 0, stream>>>(weight, attn, Wagg);
  conv_kernel<<<2048, 256, 0, stream>>>(x, Wagg, aggb, out);
}

// Round 9
// 112.609 us; speedup vs baseline: 1.5160x; 1.5160x over previous
//
#include <hip/hip_runtime.h>
#include <cstdint>
#include <cstddef>

typedef __bf16 bf16;
typedef bf16 bf16x8 __attribute__((ext_vector_type(8)));
typedef float f32x4 __attribute__((ext_vector_type(4)));

typedef __attribute__((address_space(1))) void as1_void;
typedef __attribute__((address_space(3))) void as3_void;

__device__ __forceinline__ void gload16(const void* g, void* l) {
  __builtin_amdgcn_global_load_lds((const as1_void*)g, (as3_void*)l, 16, 0, 0);
}
#define SBAR()   __builtin_amdgcn_s_barrier()
#define LGKM0()  do { asm volatile("s_waitcnt lgkmcnt(0)" ::: "memory"); \
                      __builtin_amdgcn_sched_barrier(0); } while (0)
#define VMCNT(n) asm volatile("s_waitcnt vmcnt(" #n ")" ::: "memory")

// ---------------- attention (tiny, exact f32) ----------------
__global__ __launch_bounds__(256) void attn_kernel(
    const float* __restrict__ ref, const float* __restrict__ w1,
    const float* __restrict__ w2, const float* __restrict__ b2,
    const float* __restrict__ bias, float* __restrict__ attn,
    float* __restrict__ aggb) {
  const int b = blockIdx.x, t = threadIdx.x;
  __shared__ float pooled[256];
  __shared__ float hsh[65];
  __shared__ float ash[4];
  {
    const float* r = ref + ((size_t)b * 256 + t) * 64;
    float s = 0.f;
    #pragma unroll
    for (int l = 0; l < 64; l += 4) {
      float4 v = *(const float4*)(r + l);
      s += v.x + v.y + v.z + v.w;
    }
    pooled[t] = s * (1.0f / 64.0f);
  }
  __syncthreads();
  if (t < 65) {
    const float* w = w1 + t * 256;
    float s = 0.f;
    for (int p = 0; p < 256; ++p) s += pooled[p] * w[p];
    hsh[t] = fmaxf(s, 0.f);
  }
  __syncthreads();
  if (t == 0) {
    float lg[4];
    for (int k = 0; k < 4; ++k) {
      float s = b2[k];
      for (int j = 0; j < 65; ++j) s += hsh[j] * w2[k * 65 + j];
      lg[k] = s * (1.0f / 34.0f);
    }
    float m = fmaxf(fmaxf(lg[0], lg[1]), fmaxf(lg[2], lg[3]));
    float e[4], se = 0.f;
    for (int k = 0; k < 4; ++k) { e[k] = expf(lg[k] - m); se += e[k]; }
    float inv = 1.0f / se;
    for (int k = 0; k < 4; ++k) { float a = e[k] * inv; ash[k] = a; attn[b * 4 + k] = a; }
  }
  __syncthreads();
  {
    float s = 0.f;
    for (int k = 0; k < 4; ++k) s += ash[k] * bias[k * 256 + t];
    aggb[b * 256 + t] = s;
  }
}

// ---------------- weight aggregation -> bf16, [b][o][s*256+i] ----------------
__global__ __launch_bounds__(256) void aggw_kernel(
    const float* __restrict__ weight, const float* __restrict__ attn,
    bf16* __restrict__ Wagg) {
  const int o = blockIdx.x, b = blockIdx.y, i = threadIdx.x;
  const float a0 = attn[b * 4 + 0], a1 = attn[b * 4 + 1];
  const float a2 = attn[b * 4 + 2], a3 = attn[b * 4 + 3];
  const size_t ks = (size_t)256 * 256 * 3;
  const float* w = weight + ((size_t)o * 256 + i) * 3;
  bf16* dst = Wagg + ((size_t)(b * 256 + o)) * 768 + i;
  #pragma unroll
  for (int s = 0; s < 3; ++s) {
    float v = a0 * w[s] + a1 * w[ks + s] + a2 * w[2 * ks + s] + a3 * w[3 * ks + s];
    dst[s * 256] = (bf16)v;
  }
}

// ---------------- conv-as-GEMM, 256x128 tile, phased schedule ----------------
// 512 threads / 8 waves (wm 0..3 x wn 0..1), per-wave 64x64, acc = 4x4 frags.
// W: 3-deep LDS ring staged TWO K-steps ahead via global_load_lds -> end-of-
// step waits are counted vmcnt (12/4), never a full drain in steady state.
// Per K-step: 2 phases {8 ds_read_b128; 2 gload_lds; barrier; lgkmcnt(0);
// setprio(1); 16 MFMA; setprio(0); barrier}  (T3+T4+T5, m201 shape).
// X: 130x64 bf16 tile per i-block, reg-staged f32->bf16 transpose (XOR
// swizzle on both write and read sides), double-barrier swap.
__global__ __launch_bounds__(512, 2) void conv_kernel(
    const float* __restrict__ x, const bf16* __restrict__ Wagg,
    const float* __restrict__ aggb, float* __restrict__ out) {
  __shared__ bf16 Wl[3][256 * 64];   // 96 KB ring
  __shared__ bf16 Xl[130 * 64];      // 16.25 KB
  const int tid = threadIdx.x;
  const int lane = tid & 63, wid = tid >> 6;
  // XCD swizzle: 1024 blocks, 8 XCDs -> 128 consecutive swz ids per XCD.
  const int bid = blockIdx.x;
  const int swz = (bid & 7) * 128 + (bid >> 3);
  const int b  = swz >> 5;
  const int lt = swz & 31;
  const int l0 = lt * 128;
  const int wm = wid >> 1, wn = wid & 1;
  const float* xb = x + (size_t)b * 256 * 4096;
  const bf16* Wb = Wagg + (size_t)b * 256 * 768;
  f32x4 acc[4][4] = {};

  // W staging: slice k = (slice%3)*256 + (slice/3)*64; half 0 = rows 0..127.
  auto stage_w_half = [&](int slice, int half) {
    const int ss = slice % 3, ibb = slice / 3;
    const int koff = ss * 256 + ibb * 64;
    #pragma unroll
    for (int r = half * 2; r < half * 2 + 2; ++r) {
      int c = r * 512 + tid;
      int row = c >> 3, subg = (c & 7) ^ (row & 7);
      gload16(Wb + (size_t)row * 768 + koff + subg * 8,
              (char*)&Wl[slice % 3][0] + (r * 512 + wid * 64) * 16);
    }
  };

  // ---- X staging: wave wid owns i-octet, lane covers 2 l-rows ----
  const float* xq = xb + (size_t)(wid * 8) * 4096 + l0 + lane * 2;
  const int ei = tid >> 1;                       // tid<128: edge i 0..63
  const int erow = (tid & 1) ? 129 : 0;
  const int el = (tid & 1) ? (l0 + 128) : (l0 - 1);
  const bool edge_ok = (el >= 0) && (el < 4096);
  float2 xv[8];
  float ev = 0.f;

  auto load_x = [&](int ib) {
    const float* p = xq + (size_t)ib * 64 * 4096;
    #pragma unroll
    for (int r = 0; r < 8; ++r)
      xv[r] = *(const float2*)(p + (size_t)r * 4096);
    if (tid < 128)
      ev = edge_ok ? xb[(size_t)(ib * 64 + ei) * 4096 + el] : 0.f;
  };
  auto write_x = [&]() {
    char* base = (char*)&Xl[0];
    #pragma unroll
    for (int q = 0; q < 2; ++q) {
      const int row = lane * 2 + 1 + q;
      bf16x8 pk;
      #pragma unroll
      for (int r = 0; r < 8; ++r) pk[r] = (bf16)(q ? xv[r].y : xv[r].x);
      *(bf16x8*)(base + row * 128 + ((wid ^ (row & 7)) << 4)) = pk;
    }
    if (tid < 128)
      *(bf16*)(base + erow * 128 + (((ei >> 3) ^ (erow & 7)) << 4) + (ei & 7) * 2)
          = (bf16)ev;
  };

  // ---- prologue: X tile 0 + W slices 0,1 (slice 0 drained, 1 in flight) ----
  load_x(0);
  write_x();
  stage_w_half(0, 0); stage_w_half(0, 1);
  stage_w_half(1, 0); stage_w_half(1, 1);
  LGKM0();          // X ds_writes visible to all waves after barrier
  VMCNT(4);         // slice0 drained; slice1 stays in flight
  SBAR();

  #pragma unroll
  for (int t = 0; t < 12; ++t) {
    const int s = t % 3, ib = t / 3;
    const char* wbuf = (const char*)&Wl[t % 3][0];
    const char* xbuf = (const char*)&Xl[0];
    #pragma unroll
    for (int kk = 0; kk < 2; ++kk) {
      const int sub = (lane >> 4) + kk * 4;
      bf16x8 af[4], bfr[4];
      #pragma unroll
      for (int j = 0; j < 4; ++j) {
        int row = wm * 64 + j * 16 + (lane & 15);
        af[j] = *(const bf16x8*)(wbuf + row * 128 + ((sub ^ (row & 7)) << 4));
      }
      #pragma unroll
      for (int n = 0; n < 4; ++n) {
        int row = wn * 64 + n * 16 + (lane & 15) + s;   // +s = conv shift
        bfr[n] = *(const bf16x8*)(xbuf + row * 128 + ((sub ^ (row & 7)) << 4));
      }
      if (t < 10) stage_w_half(t + 2, kk);              // prefetch depth 2
      if (kk == 1 && s == 0 && ib < 3) load_x(ib + 1);  // after W issues
      SBAR();
      LGKM0();
      __builtin_amdgcn_s_setprio(1);
      #pragma unroll
      for (int j = 0; j < 4; ++j)
        #pragma unroll
        for (int n = 0; n < 4; ++n)
          acc[j][n] = __builtin_amdgcn_mfma_f32_16x16x32_bf16(af[j], bfr[n], acc[j][n], 0, 0, 0);
      __builtin_amdgcn_s_setprio(0);
      if (kk == 0) {
        SBAR();
      } else if (s < 2) {
        // end of step t: drain slice t+1's loads (issued at t-1), keep newer
        if (ib < 3)      { VMCNT(12); }   // keep W(t)4 + xv8
        else if (t == 9) { VMCNT(4);  }   // keep W(t)4 (no xv at ib=3)
        else             { VMCNT(0);  }   // t == 10: drain slice 11
        SBAR();
      } else if (t < 11) {
        SBAR();            // all waves' X reads returned
        write_x();         // next i-block's tile (xv drained by compiler)
        LGKM0();           // this wave's ds_writes done
        VMCNT(4);          // drain slice t+1, keep slice t+2
        SBAR();            // writes visible to all
      }
      // t == 11, kk == 1: fall through to epilogue
    }
  }

  const int b256 = b * 256;
  #pragma unroll
  for (int j = 0; j < 4; ++j) {
    const int ob = wm * 64 + j * 16 + ((lane >> 4) << 2);
    float bb[4];
    #pragma unroll
    for (int r = 0; r < 4; ++r) bb[r] = aggb[b256 + ob + r];
    #pragma unroll
    for (int n = 0; n < 4; ++n) {
      const int l = l0 + wn * 64 + n * 16 + (lane & 15);
      f32x4 v = acc[j][n];
      #pragma unroll
      for (int r = 0; r < 4; ++r)
        out[((size_t)(b256 + ob + r)) * 4096 + l] = v[r] + bb[r];
    }
  }
}

extern "C" void kernel_launch(void* const* d_in, const int* in_sizes, int n_in,
                              void* d_out, int out_size, void* d_ws, size_t ws_size,
                              hipStream_t stream) {
  const float* ref    = (const float*)d_in[0];
  const float* x      = (const float*)d_in[1];
  const float* w1     = (const float*)d_in[2];
  const float* w2     = (const float*)d_in[3];
  const float* b2     = (const float*)d_in[4];
  const float* weight = (const float*)d_in[5];
  const float* bias   = (const float*)d_in[6];
  float* out = (float*)d_out;
  char* ws = (char*)d_ws;

  const size_t WAGG_BYTES = (size_t)32 * 256 * 768 * 2;    // 12,582,912
  bf16* Wagg  = (bf16*)ws;
  float* attn = (float*)(ws + WAGG_BYTES);
  float* aggb = (float*)(ws + WAGG_BYTES + 512);

  attn_kernel<<<32, 256, 0, stream>>>(ref, w1, w2, b2, bias, attn, aggb);
  aggw_kernel<<<dim3(256, 32), 256, 0, stream>>>(weight, attn, Wagg);
  conv_kernel<<<1024, 512, 0, stream>>>(x, Wagg, aggb, out);
}

// Round 10
// 101.013 us; speedup vs baseline: 1.6901x; 1.1148x over previous
//
#include <hip/hip_runtime.h>
#include <cstdint>
#include <cstddef>

typedef __bf16 bf16;
typedef bf16 bf16x8 __attribute__((ext_vector_type(8)));
typedef float f32x4 __attribute__((ext_vector_type(4)));

typedef __attribute__((address_space(1))) void as1_void;
typedef __attribute__((address_space(3))) void as3_void;

__device__ __forceinline__ void gload16(const void* g, void* l) {
  __builtin_amdgcn_global_load_lds((const as1_void*)g, (as3_void*)l, 16, 0, 0);
}
#define SBAR()   __builtin_amdgcn_s_barrier()
#define LGKM0()  do { asm volatile("s_waitcnt lgkmcnt(0)" ::: "memory"); \
                      __builtin_amdgcn_sched_barrier(0); } while (0)
#define VMCNT(n) asm volatile("s_waitcnt vmcnt(" #n ")" ::: "memory")

// ---------------- attention (tiny, exact f32) ----------------
__global__ __launch_bounds__(256) void attn_kernel(
    const float* __restrict__ ref, const float* __restrict__ w1,
    const float* __restrict__ w2, const float* __restrict__ b2,
    const float* __restrict__ bias, float* __restrict__ attn,
    float* __restrict__ aggb) {
  const int b = blockIdx.x, t = threadIdx.x;
  __shared__ float pooled[256];
  __shared__ float hsh[65];
  __shared__ float ash[4];
  {
    const float* r = ref + ((size_t)b * 256 + t) * 64;
    float s = 0.f;
    #pragma unroll
    for (int l = 0; l < 64; l += 4) {
      float4 v = *(const float4*)(r + l);
      s += v.x + v.y + v.z + v.w;
    }
    pooled[t] = s * (1.0f / 64.0f);
  }
  __syncthreads();
  if (t < 65) {
    const float* w = w1 + t * 256;
    float s = 0.f;
    for (int p = 0; p < 256; ++p) s += pooled[p] * w[p];
    hsh[t] = fmaxf(s, 0.f);
  }
  __syncthreads();
  if (t == 0) {
    float lg[4];
    for (int k = 0; k < 4; ++k) {
      float s = b2[k];
      for (int j = 0; j < 65; ++j) s += hsh[j] * w2[k * 65 + j];
      lg[k] = s * (1.0f / 34.0f);
    }
    float m = fmaxf(fmaxf(lg[0], lg[1]), fmaxf(lg[2], lg[3]));
    float e[4], se = 0.f;
    for (int k = 0; k < 4; ++k) { e[k] = expf(lg[k] - m); se += e[k]; }
    float inv = 1.0f / se;
    for (int k = 0; k < 4; ++k) { float a = e[k] * inv; ash[k] = a; attn[b * 4 + k] = a; }
  }
  __syncthreads();
  {
    float s = 0.f;
    for (int k = 0; k < 4; ++k) s += ash[k] * bias[k * 256 + t];
    aggb[b * 256 + t] = s;
  }
}

// ---------------- weight aggregation -> bf16, [b][o][s*256+i] ----------------
__global__ __launch_bounds__(256) void aggw_kernel(
    const float* __restrict__ weight, const float* __restrict__ attn,
    bf16* __restrict__ Wagg) {
  const int o = blockIdx.x, b = blockIdx.y, i = threadIdx.x;
  const float a0 = attn[b * 4 + 0], a1 = attn[b * 4 + 1];
  const float a2 = attn[b * 4 + 2], a3 = attn[b * 4 + 3];
  const size_t ks = (size_t)256 * 256 * 3;
  const float* w = weight + ((size_t)o * 256 + i) * 3;
  bf16* dst = Wagg + ((size_t)(b * 256 + o)) * 768 + i;
  #pragma unroll
  for (int s = 0; s < 3; ++s) {
    float v = a0 * w[s] + a1 * w[ks + s] + a2 * w[2 * ks + s] + a3 * w[3 * ks + s];
    dst[s * 256] = (bf16)v;
  }
}

// ---------------- conv-as-GEMM, 256x256 block, m201 geometry ----------------
// 512 threads / 8 waves; wave tile 128x64 (12 ds_read_b128 : 32 MFMA per
// phase -> MFMA-dominant pipe balance, the ratio R9 lacked). W: 3-slice LDS
// ring staged depth-2 via global_load_lds, counted VMCNT(4) at step ends
// (never 0 in steady state). X: 258x64 bf16 tile per i-block, reg-staged
// f32->bf16 transpose, XOR swizzle both sides, boundary swap with barriers.
__global__ __launch_bounds__(512) void conv_kernel(
    const float* __restrict__ x, const bf16* __restrict__ Wagg,
    const float* __restrict__ aggb, float* __restrict__ out) {
  __shared__ bf16 Wl[3][256 * 64];   // 96 KB ring
  __shared__ bf16 Xl[258 * 64];      // 33 KB  (rows l0-1 .. l0+256)
  const int tid = threadIdx.x;
  const int lane = tid & 63, wid = tid >> 6;
  // XCD swizzle: 512 blocks, 8 XCDs -> 64 consecutive swz ids per XCD
  // = 4 batches per XCD (Wagg 1.5 MB L2-hot).
  const int bid = blockIdx.x;
  const int swz = (bid & 7) * 64 + (bid >> 3);
  const int b  = swz >> 4;
  const int lt = swz & 15;
  const int l0 = lt * 256;
  const int wm = wid >> 2, wn = wid & 3;
  const float* xb = x + (size_t)b * 256 * 4096;
  const bf16* Wb = Wagg + (size_t)b * 256 * 768;
  f32x4 acc[8][4] = {};

  // W staging: slice (s,ib) -> k = (slice%3)*256 + (slice/3)*64, rows 0..255.
  auto stage_w_half = [&](int slice, int half) {
    const int ss = slice % 3, ibb = slice / 3;
    const int koff = ss * 256 + ibb * 64;
    char* base = (char*)&Wl[slice % 3][0];
    #pragma unroll
    for (int r = half * 2; r < half * 2 + 2; ++r) {
      int c = r * 512 + tid;
      int row = c >> 3, subg = (c & 7) ^ (row & 7);
      gload16(Wb + (size_t)row * 768 + koff + subg * 8,
              base + (r * 512 + wid * 64) * 16);
    }
  };

  // ---- X staging: sg = i-octet (0..7), lq = l-quad (0..63) ----
  const int sg = tid >> 6, lq = tid & 63;
  const float* xq = xb + ((size_t)sg * 8) * 4096 + l0 + lq * 4;
  const int ei = tid >> 1;                       // tid<128: edge i 0..63
  const int erow = (tid & 1) ? 257 : 0;
  const int el = (tid & 1) ? (l0 + 256) : (l0 - 1);
  const bool edge_ok = (el >= 0) && (el < 4096);
  float4 xv[8];
  float ev = 0.f;

  auto load_x = [&](int ib) {
    const float* p = xq + (size_t)ib * 64 * 4096;
    #pragma unroll
    for (int r = 0; r < 8; ++r)
      xv[r] = *(const float4*)(p + (size_t)r * 4096);
    if (tid < 128)
      ev = edge_ok ? xb[(size_t)(ib * 64 + ei) * 4096 + el] : 0.f;
  };
  auto write_x = [&]() {
    char* base = (char*)&Xl[0];
    #pragma unroll
    for (int q = 0; q < 4; ++q) {
      const int row = lq * 4 + 1 + q;
      bf16x8 pk;
      #pragma unroll
      for (int r = 0; r < 8; ++r) pk[r] = (bf16)(((const float*)&xv[r])[q]);
      *(bf16x8*)(base + row * 128 + ((sg ^ (row & 7)) << 4)) = pk;
    }
    if (tid < 128)
      *(bf16*)(base + erow * 128 + (((ei >> 3) ^ (erow & 7)) << 4) + (ei & 7) * 2)
          = (bf16)ev;
  };

  // ---- prologue: X tile 0; W slices 0 (drained) and 1 (in flight) ----
  load_x(0);
  write_x();
  stage_w_half(0, 0); stage_w_half(0, 1);
  stage_w_half(1, 0); stage_w_half(1, 1);
  LGKM0();          // this wave's ds_writes done
  VMCNT(4);         // slice0 landed; slice1 stays in flight
  SBAR();           // X + W0 visible to all waves

  for (int t = 0; t < 12; ++t) {
    const int s = t % 3, ib = t / 3;
    const char* wbuf = (const char*)&Wl[t % 3][0];
    const char* xbuf = (const char*)&Xl[0];
    #pragma unroll
    for (int kk = 0; kk < 2; ++kk) {
      const int sub = (lane >> 4) + kk * 4;
      bf16x8 af[8], bfr[4];
      #pragma unroll
      for (int j = 0; j < 8; ++j) {
        int row = wm * 128 + j * 16 + (lane & 15);
        af[j] = *(const bf16x8*)(wbuf + row * 128 + ((sub ^ (row & 7)) << 4));
      }
      #pragma unroll
      for (int n = 0; n < 4; ++n) {
        int row = wn * 64 + n * 16 + (lane & 15) + s;   // +s = conv shift
        bfr[n] = *(const bf16x8*)(xbuf + row * 128 + ((sub ^ (row & 7)) << 4));
      }
      if (t < 10) stage_w_half(t + 2, kk);              // ring depth 2
      if (kk == 1 && s == 2 && ib < 3) load_x(ib + 1);  // issued after W
      SBAR();
      LGKM0();
      __builtin_amdgcn_s_setprio(1);
      #pragma unroll
      for (int j = 0; j < 8; ++j)
        #pragma unroll
        for (int n = 0; n < 4; ++n)
          acc[j][n] = __builtin_amdgcn_mfma_f32_16x16x32_bf16(af[j], bfr[n], acc[j][n], 0, 0, 0);
      __builtin_amdgcn_s_setprio(0);
      if (kk == 0) {
        SBAR();
      } else if (s < 2) {
        // end of step t: slice t+1 must be landed for step t+1
        if (t == 10) { VMCNT(0); } else { VMCNT(4); }
        SBAR();
      } else if (t < 11) {
        SBAR();            // all waves done reading Xl for this ib
        write_x();         // compiler drains xv progressively (incl. W t+1)
        LGKM0();           // this wave's ds_writes done
        SBAR();            // new X tile visible to all
      }
      // t==11, kk==1: fall through to epilogue
    }
  }

  const int b256 = b * 256;
  #pragma unroll
  for (int j = 0; j < 8; ++j) {
    const int ob = wm * 128 + j * 16 + ((lane >> 4) << 2);
    float bb[4];
    #pragma unroll
    for (int r = 0; r < 4; ++r) bb[r] = aggb[b256 + ob + r];
    #pragma unroll
    for (int n = 0; n < 4; ++n) {
      const int l = l0 + wn * 64 + n * 16 + (lane & 15);
      f32x4 v = acc[j][n];
      #pragma unroll
      for (int r = 0; r < 4; ++r)
        out[((size_t)(b256 + ob + r)) * 4096 + l] = v[r] + bb[r];
    }
  }
}

extern "C" void kernel_launch(void* const* d_in, const int* in_sizes, int n_in,
                              void* d_out, int out_size, void* d_ws, size_t ws_size,
                              hipStream_t stream) {
  const float* ref    = (const float*)d_in[0];
  const float* x      = (const float*)d_in[1];
  const float* w1     = (const float*)d_in[2];
  const float* w2     = (const float*)d_in[3];
  const float* b2     = (const float*)d_in[4];
  const float* weight = (const float*)d_in[5];
  const float* bias   = (const float*)d_in[6];
  float* out = (float*)d_out;
  char* ws = (char*)d_ws;

  const size_t WAGG_BYTES = (size_t)32 * 256 * 768 * 2;    // 12,582,912
  bf16* Wagg  = (bf16*)ws;
  float* attn = (float*)(ws + WAGG_BYTES);
  float* aggb = (float*)(ws + WAGG_BYTES + 512);

  attn_kernel<<<32, 256, 0, stream>>>(ref, w1, w2, b2, bias, attn, aggb);
  aggw_kernel<<<dim3(256, 32), 256, 0, stream>>>(weight, attn, Wagg);
  conv_kernel<<<512, 512, 0, stream>>>(x, Wagg, aggb, out);
}